// Round 10
// baseline (406.784 us; speedup 1.0000x reference)
//
#include <hip/hip_runtime.h>
#include <hip/hip_bf16.h>

// ---------------------------------------------------------------------------
// EdgeClassifier: 2x GCNConv + edge MLP. All node intermediates bf16.
// Layer 1 aggregates in x-space (32-dim, 64B rows = 1 line/gather):
//   xs = bf16(x*dinv) -> agg_x -> node1: h1s = relu(xagg@W1+b1)*dinv
// Layer 2 aggregate-first: agg2(h1s) -> node2: h2 = xagg2@W2+b2
// Edge MLP: R9 coop-gather structure + XOR-swizzled slab (conflict fix),
//   eattr pre-converted to bf16 when workspace allows (ws_size guard).
// ---------------------------------------------------------------------------

typedef __attribute__((ext_vector_type(8))) short  bf16x8;
typedef __attribute__((ext_vector_type(16))) float f32x16;

__device__ inline short f2bf(float f)
{
    union { float f; unsigned u; } v; v.f = f;
    unsigned r = v.u + 0x7fff + ((v.u >> 16) & 1);   // RNE
    return (short)(r >> 16);
}

__device__ inline float2 bfp2f(unsigned u)
{
    union { unsigned u; float f; } a, b;
    a.u = u << 16;
    b.u = u & 0xffff0000u;
    return make_float2(a.f, b.f);
}

__device__ inline unsigned packbf2(float a, float b)
{
    return (unsigned)(unsigned short)f2bf(a) | ((unsigned)(unsigned short)f2bf(b) << 16);
}

// ---------------- CSR build ----------------
__global__ __launch_bounds__(256) void k_hist(const int* __restrict__ ei, int* __restrict__ degcnt, int E)
{
    int e = blockIdx.x * 256 + threadIdx.x;
    if (e < E) atomicAdd(&degcnt[ei[E + e]], 1);
}

__global__ __launch_bounds__(256) void k_dinv_bsum(const int* __restrict__ degcnt, float* __restrict__ dinv,
                                                   int n, int* __restrict__ bsum)
{
    __shared__ int s[256];
    int t = threadIdx.x;
    int i = blockIdx.x * 256 + t;
    int dg = (i < n) ? degcnt[i] : 0;
    if (i < n) dinv[i] = rsqrtf((float)(dg + 1));
    s[t] = dg;
    __syncthreads();
    for (int o = 128; o > 0; o >>= 1) {
        if (t < o) s[t] += s[t + o];
        __syncthreads();
    }
    if (t == 0) bsum[blockIdx.x] = s[0];
}

__global__ __launch_bounds__(512) void k_boff(const int* __restrict__ bsum, int nb, int* __restrict__ boff)
{
    __shared__ int s[512];
    int t = threadIdx.x;
    int v = (t < nb) ? bsum[t] : 0;
    s[t] = v;
    __syncthreads();
    for (int o = 1; o < 512; o <<= 1) {
        int a = (t >= o) ? s[t - o] : 0;
        __syncthreads();
        s[t] += a;
        __syncthreads();
    }
    if (t < nb) boff[t] = s[t] - v;
}

__global__ __launch_bounds__(256) void k_rowstart(const int* __restrict__ deg, const int* __restrict__ boff,
                                                  int* __restrict__ rs, int n, int total)
{
    __shared__ int s[256];
    int t = threadIdx.x;
    int i = blockIdx.x * 256 + t;
    int v = (i < n) ? deg[i] : 0;
    s[t] = v;
    __syncthreads();
    for (int o = 1; o < 256; o <<= 1) {
        int a = (t >= o) ? s[t - o] : 0;
        __syncthreads();
        s[t] += a;
        __syncthreads();
    }
    if (i < n) rs[i] = boff[blockIdx.x] + s[t] - v;
    if (i == 0) rs[n] = total;
}

__global__ __launch_bounds__(256) void k_scatter(const int* __restrict__ ei, const int* __restrict__ rs,
                                                 int* __restrict__ cursor, int* __restrict__ col, int E)
{
    int e = blockIdx.x * 256 + threadIdx.x;
    if (e < E) {
        int d = ei[E + e];
        int pos = atomicAdd(&cursor[d], 1);
        col[rs[d] + pos] = ei[e];
    }
}

// ---------------- weight prep (all bf16, transposed) ----------------
__global__ __launch_bounds__(256) void k_prep(const float* __restrict__ Wc1, const float* __restrict__ Wc2,
                                              const float* __restrict__ W2, const float* __restrict__ W1,
                                              short* __restrict__ Wc1T, short* __restrict__ Wc2T,
                                              short* __restrict__ W2T, short* __restrict__ W1T)
{
    int t = blockIdx.x * 256 + threadIdx.x;
    if (t < 9216) {
        int j = t / 144, k = t - j * 144;
        Wc1T[t] = f2bf(Wc1[k * 64 + j]);
    } else if (t < 11264) {
        int u = t - 9216;
        int rr = u / 64, k = u - rr * 64;
        Wc2T[u] = (rr < 5) ? f2bf(Wc2[k * 5 + rr]) : (short)0;
    } else if (t < 15360) {
        int u = t - 11264;
        int j = u / 64, k = u - j * 64;
        W2T[u] = f2bf(W2[k * 64 + j]);
    } else if (t < 17408) {
        int u = t - 15360;
        int j = u / 32, k = u - j * 32;
        W1T[u] = f2bf(W1[k * 64 + j]);
    }
}

// ---------------- xs = bf16(x * dinv)  (N x 32) ----------------
__global__ __launch_bounds__(256) void k_xs(const float* __restrict__ x, const float* __restrict__ dinv,
                                            unsigned short* __restrict__ xs, int n)
{
    int id = blockIdx.x * 256 + threadIdx.x;     // one thread per 2 channels
    int v = id >> 4, l = id & 15;
    if (v >= n) return;
    float2 xv = *(const float2*)&x[(size_t)v * 32 + l * 2];
    float dv = dinv[v];
    *(unsigned*)(xs + (size_t)v * 32 + l * 2) = packbf2(xv.x * dv, xv.y * dv);
}

// ---------------- eattr -> bf16 (optional, ws-guarded) ----------------
__global__ __launch_bounds__(256) void k_ea(const float* __restrict__ ea, unsigned short* __restrict__ eabf, long n4)
{
    long id = (long)blockIdx.x * 256 + threadIdx.x;   // one thread per 4 floats
    if (id >= n4) return;
    float4 v = *(const float4*)&ea[id * 4];
    short4 o;
    o.x = f2bf(v.x); o.y = f2bf(v.y); o.z = f2bf(v.z); o.w = f2bf(v.w);
    *(short4*)&eabf[id * 4] = o;
}

// ---------------- x-space aggregation: xagg[v] = dinv[v]*(xs[v]+sum xs[u]) ----------------
// 16 nodes/block, 16 lanes/node, 64B rows = 1 line per gather.
__global__ __launch_bounds__(256) void k_agg_x(const unsigned short* __restrict__ xs,
                                               const float* __restrict__ dinv,
                                               const int* __restrict__ rs, const int* __restrict__ col,
                                               unsigned short* __restrict__ xagg, int n)
{
    const int tid = threadIdx.x;
    const int l   = tid & 15;
    const int v   = blockIdx.x * 16 + (tid >> 4);
    if (v >= n) return;

    float2 acc = bfp2f(*(const unsigned*)(xs + (size_t)v * 32 + l * 2));   // self
    int i = rs[v];
    const int end = rs[v + 1];
    for (; i + 8 <= end; i += 8) {
        int c0 = col[i],     c1 = col[i + 1], c2 = col[i + 2], c3 = col[i + 3];
        int c4 = col[i + 4], c5 = col[i + 5], c6 = col[i + 6], c7 = col[i + 7];
        unsigned u0 = *(const unsigned*)(xs + (size_t)c0 * 32 + l * 2);
        unsigned u1 = *(const unsigned*)(xs + (size_t)c1 * 32 + l * 2);
        unsigned u2 = *(const unsigned*)(xs + (size_t)c2 * 32 + l * 2);
        unsigned u3 = *(const unsigned*)(xs + (size_t)c3 * 32 + l * 2);
        unsigned u4 = *(const unsigned*)(xs + (size_t)c4 * 32 + l * 2);
        unsigned u5 = *(const unsigned*)(xs + (size_t)c5 * 32 + l * 2);
        unsigned u6 = *(const unsigned*)(xs + (size_t)c6 * 32 + l * 2);
        unsigned u7 = *(const unsigned*)(xs + (size_t)c7 * 32 + l * 2);
        float2 a0 = bfp2f(u0), a1 = bfp2f(u1), a2 = bfp2f(u2), a3 = bfp2f(u3);
        float2 a4 = bfp2f(u4), a5 = bfp2f(u5), a6 = bfp2f(u6), a7 = bfp2f(u7);
        acc.x += (a0.x + a1.x) + (a2.x + a3.x) + (a4.x + a5.x) + (a6.x + a7.x);
        acc.y += (a0.y + a1.y) + (a2.y + a3.y) + (a4.y + a5.y) + (a6.y + a7.y);
    }
    for (; i < end; ++i) {
        float2 a = bfp2f(*(const unsigned*)(xs + (size_t)col[i] * 32 + l * 2));
        acc.x += a.x; acc.y += a.y;
    }
    const float dv = dinv[v];
    *(unsigned*)(xagg + (size_t)v * 32 + l * 2) = packbf2(dv * acc.x, dv * acc.y);
}

// ---------------- 64-dim aggregation (no bias): xagg2[v] = dinv[v]*(self+sum) ----------------
__global__ __launch_bounds__(256) void k_agg64(const unsigned short* __restrict__ hsc,
                                               const float* __restrict__ dinv,
                                               const int* __restrict__ rs, const int* __restrict__ col,
                                               unsigned short* __restrict__ out, int n)
{
    const int tid = threadIdx.x;
    const int l   = tid & 31;
    const int v   = blockIdx.x * 8 + (tid >> 5);
    if (v >= n) return;

    float2 acc = bfp2f(*(const unsigned*)(hsc + (size_t)v * 64 + l * 2));
    int i = rs[v];
    const int end = rs[v + 1];
    for (; i + 8 <= end; i += 8) {
        int c0 = col[i],     c1 = col[i + 1], c2 = col[i + 2], c3 = col[i + 3];
        int c4 = col[i + 4], c5 = col[i + 5], c6 = col[i + 6], c7 = col[i + 7];
        unsigned u0 = *(const unsigned*)(hsc + (size_t)c0 * 64 + l * 2);
        unsigned u1 = *(const unsigned*)(hsc + (size_t)c1 * 64 + l * 2);
        unsigned u2 = *(const unsigned*)(hsc + (size_t)c2 * 64 + l * 2);
        unsigned u3 = *(const unsigned*)(hsc + (size_t)c3 * 64 + l * 2);
        unsigned u4 = *(const unsigned*)(hsc + (size_t)c4 * 64 + l * 2);
        unsigned u5 = *(const unsigned*)(hsc + (size_t)c5 * 64 + l * 2);
        unsigned u6 = *(const unsigned*)(hsc + (size_t)c6 * 64 + l * 2);
        unsigned u7 = *(const unsigned*)(hsc + (size_t)c7 * 64 + l * 2);
        float2 a0 = bfp2f(u0), a1 = bfp2f(u1), a2 = bfp2f(u2), a3 = bfp2f(u3);
        float2 a4 = bfp2f(u4), a5 = bfp2f(u5), a6 = bfp2f(u6), a7 = bfp2f(u7);
        acc.x += (a0.x + a1.x) + (a2.x + a3.x) + (a4.x + a5.x) + (a6.x + a7.x);
        acc.y += (a0.y + a1.y) + (a2.y + a3.y) + (a4.y + a5.y) + (a6.y + a7.y);
    }
    for (; i < end; ++i) {
        float2 a = bfp2f(*(const unsigned*)(hsc + (size_t)col[i] * 64 + l * 2));
        acc.x += a.x; acc.y += a.y;
    }
    const float dv = dinv[v];
    *(unsigned*)(out + (size_t)v * 64 + l * 2) = packbf2(dv * acc.x, dv * acc.y);
}

// ---------------- node1: h1s = relu(xagg @ W1 + b1) * dinv  (MFMA, swapped) ----------------
// A = W1T rows (j), B = xagg node cols. C/D: col=lane&31 = node, row=reg = j.
__global__ __launch_bounds__(256) void k_node1(const unsigned short* __restrict__ xagg,
                                               const short* __restrict__ W1T,
                                               const float* __restrict__ b1, const float* __restrict__ dinv,
                                               unsigned short* __restrict__ h1s, int n)
{
    const int tid = threadIdx.x;
    const int w = tid >> 6, lane = tid & 63, r = lane & 31, kg = lane >> 5;
    const int nb = blockIdx.x * 128 + w * 32;

    bf16x8 a0[2], a1[2];
#pragma unroll
    for (int t = 0; t < 2; ++t) {
        a0[t] = *(const bf16x8*)&W1T[r * 32 + t * 16 + kg * 8];
        a1[t] = *(const bf16x8*)&W1T[(r + 32) * 32 + t * 16 + kg * 8];
    }

    int row = nb + r;
    if (row >= n) row = n - 1;
    f32x16 acc0 = {0.f}, acc1 = {0.f};
#pragma unroll
    for (int t = 0; t < 2; ++t) {
        bf16x8 b = *(const bf16x8*)&xagg[(size_t)row * 32 + t * 16 + kg * 8];
        acc0 = __builtin_amdgcn_mfma_f32_32x32x16_bf16(a0[t], b, acc0, 0, 0, 0);
        acc1 = __builtin_amdgcn_mfma_f32_32x32x16_bf16(a1[t], b, acc1, 0, 0, 0);
    }

    const int node = nb + r;
    if (node < n) {
        const float dv = dinv[node];
#pragma unroll
        for (int q = 0; q < 4; ++q) {
            const int j0 = 8 * q + 4 * kg;
            float4 bA = *(const float4*)&b1[j0];
            float4 bB = *(const float4*)&b1[j0 + 32];
            short4 s0, s1;
            float t0, t1;
            t0 = acc0[4 * q]     + bA.x; t0 = t0 > 0.f ? t0 : 0.f; s0.x = f2bf(t0 * dv);
            t0 = acc0[4 * q + 1] + bA.y; t0 = t0 > 0.f ? t0 : 0.f; s0.y = f2bf(t0 * dv);
            t0 = acc0[4 * q + 2] + bA.z; t0 = t0 > 0.f ? t0 : 0.f; s0.z = f2bf(t0 * dv);
            t0 = acc0[4 * q + 3] + bA.w; t0 = t0 > 0.f ? t0 : 0.f; s0.w = f2bf(t0 * dv);
            t1 = acc1[4 * q]     + bB.x; t1 = t1 > 0.f ? t1 : 0.f; s1.x = f2bf(t1 * dv);
            t1 = acc1[4 * q + 1] + bB.y; t1 = t1 > 0.f ? t1 : 0.f; s1.y = f2bf(t1 * dv);
            t1 = acc1[4 * q + 2] + bB.z; t1 = t1 > 0.f ? t1 : 0.f; s1.z = f2bf(t1 * dv);
            t1 = acc1[4 * q + 3] + bB.w; t1 = t1 > 0.f ? t1 : 0.f; s1.w = f2bf(t1 * dv);
            *(short4*)&h1s[(size_t)node * 64 + j0]      = s0;
            *(short4*)&h1s[(size_t)node * 64 + j0 + 32] = s1;
        }
    }
}

// ---------------- node2: h2 = xagg2 @ W2 + b2  (MFMA, swapped) ----------------
__global__ __launch_bounds__(256) void k_node2(const unsigned short* __restrict__ xagg2,
                                               const short* __restrict__ W2T,
                                               const float* __restrict__ b2,
                                               unsigned short* __restrict__ h2, int n)
{
    const int tid = threadIdx.x;
    const int w = tid >> 6, lane = tid & 63, r = lane & 31, kg = lane >> 5;
    const int nb = blockIdx.x * 128 + w * 32;

    bf16x8 a0[4], a1[4];
#pragma unroll
    for (int t = 0; t < 4; ++t) {
        a0[t] = *(const bf16x8*)&W2T[r * 64 + t * 16 + kg * 8];
        a1[t] = *(const bf16x8*)&W2T[(r + 32) * 64 + t * 16 + kg * 8];
    }

    int row = nb + r;
    if (row >= n) row = n - 1;
    f32x16 acc0 = {0.f}, acc1 = {0.f};
#pragma unroll
    for (int t = 0; t < 4; ++t) {
        bf16x8 b = *(const bf16x8*)&xagg2[(size_t)row * 64 + t * 16 + kg * 8];
        acc0 = __builtin_amdgcn_mfma_f32_32x32x16_bf16(a0[t], b, acc0, 0, 0, 0);
        acc1 = __builtin_amdgcn_mfma_f32_32x32x16_bf16(a1[t], b, acc1, 0, 0, 0);
    }

    const int node = nb + r;
    if (node < n) {
#pragma unroll
        for (int q = 0; q < 4; ++q) {
            const int j0 = 8 * q + 4 * kg;
            float4 bA = *(const float4*)&b2[j0];
            float4 bB = *(const float4*)&b2[j0 + 32];
            short4 s0, s1;
            s0.x = f2bf(acc0[4 * q]     + bA.x); s0.y = f2bf(acc0[4 * q + 1] + bA.y);
            s0.z = f2bf(acc0[4 * q + 2] + bA.z); s0.w = f2bf(acc0[4 * q + 3] + bA.w);
            s1.x = f2bf(acc1[4 * q]     + bB.x); s1.y = f2bf(acc1[4 * q + 1] + bB.y);
            s1.z = f2bf(acc1[4 * q + 2] + bB.z); s1.w = f2bf(acc1[4 * q + 3] + bB.w);
            *(short4*)&h2[(size_t)node * 64 + j0]      = s0;
            *(short4*)&h2[(size_t)node * 64 + j0 + 32] = s1;
        }
    }
}

// ---------------- MFMA edge MLP, coop gathers + XOR-swizzled slab ----------------
// slot(c,row) = c*512 + ((row ^ (c&3))*16); src half [0,4K), dst half [4K,8K).
template <int ABF>
__global__ __launch_bounds__(256) void k_edge_mlp_mfma(
    const unsigned short* __restrict__ h2bf, const void* __restrict__ eattr,
    const int* __restrict__ ei,
    const short* __restrict__ Wc1T, const float* __restrict__ bc1,
    const short* __restrict__ Wc2T, const float* __restrict__ bc2,
    float* __restrict__ out, int E)
{
    __shared__ char slab[4 * 8192];   // 32 KB

    const int tid = threadIdx.x;
    const int w = tid >> 6, lane = tid & 63, r = lane & 31, kg = lane >> 5;
    const int q = lane & 3, sr = lane >> 2;

    char* myslab = slab + w * 8192;
    short* hid = (short*)myslab;

    const long eb = (long)blockIdx.x * 128 + w * 32;
    long ecl = eb + r; if (ecl >= E) ecl = E - 1;
    const int ns = ei[ecl];
    const int nd = ei[E + ecl];

    // attr fragment
    bf16x8 aa;
    if (ABF) {
        aa = *(const bf16x8*)((const unsigned short*)eattr + (size_t)ecl * 16 + kg * 8);
    } else {
        const float* arow = (const float*)eattr + (size_t)ecl * 16;
        float4 alo = *(const float4*)&arow[kg * 8];
        float4 ahi = *(const float4*)&arow[kg * 8 + 4];
        aa[0] = f2bf(alo.x); aa[1] = f2bf(alo.y); aa[2] = f2bf(alo.z); aa[3] = f2bf(alo.w);
        aa[4] = f2bf(ahi.x); aa[5] = f2bf(ahi.y); aa[6] = f2bf(ahi.z); aa[7] = f2bf(ahi.w);
    }

    // coop gathers: 4-lane groups fetch contiguous 64 B per row
    {
        int n0 = __shfl(ns, sr);
        int n1 = __shfl(ns, 16 + sr);
        int m0 = __shfl(nd, sr);
        int m1 = __shfl(nd, 16 + sr);
        int4 s0 = *(const int4*)&h2bf[(size_t)n0 * 64 + q * 8];
        int4 s1 = *(const int4*)&h2bf[(size_t)n0 * 64 + 32 + q * 8];
        int4 s2 = *(const int4*)&h2bf[(size_t)n1 * 64 + q * 8];
        int4 s3 = *(const int4*)&h2bf[(size_t)n1 * 64 + 32 + q * 8];
        int4 d0 = *(const int4*)&h2bf[(size_t)m0 * 64 + q * 8];
        int4 d1 = *(const int4*)&h2bf[(size_t)m0 * 64 + 32 + q * 8];
        int4 d2 = *(const int4*)&h2bf[(size_t)m1 * 64 + q * 8];
        int4 d3 = *(const int4*)&h2bf[(size_t)m1 * 64 + 32 + q * 8];
        const int x0 = (sr ^ q) * 16, x1 = (16 + (sr ^ q)) * 16;   // row^key, key=c&3=q
        *(int4*)(myslab + q * 512 + x0)              = s0;
        *(int4*)(myslab + (4 + q) * 512 + x0)        = s1;
        *(int4*)(myslab + q * 512 + x1)              = s2;
        *(int4*)(myslab + (4 + q) * 512 + x1)        = s3;
        *(int4*)(myslab + 4096 + q * 512 + x0)       = d0;
        *(int4*)(myslab + 4096 + (4 + q) * 512 + x0) = d1;
        *(int4*)(myslab + 4096 + q * 512 + x1)       = d2;
        *(int4*)(myslab + 4096 + (4 + q) * 512 + x1) = d3;
    }

    f32x16 acc0, acc1;
    const float bias0 = bc1[r], bias1 = bc1[r + 32];
#pragma unroll
    for (int i = 0; i < 16; ++i) { acc0[i] = bias0; acc1[i] = bias1; }

#pragma unroll
    for (int t = 0; t < 4; ++t) {
        const int c = 2 * t + kg;
        bf16x8 a  = *(const bf16x8*)(myslab + c * 512 + ((r ^ (c & 3)) * 16));
        bf16x8 w0 = *(const bf16x8*)&Wc1T[r * 144 + t * 16 + kg * 8];
        bf16x8 w1 = *(const bf16x8*)&Wc1T[(r + 32) * 144 + t * 16 + kg * 8];
        acc0 = __builtin_amdgcn_mfma_f32_32x32x16_bf16(a, w0, acc0, 0, 0, 0);
        acc1 = __builtin_amdgcn_mfma_f32_32x32x16_bf16(a, w1, acc1, 0, 0, 0);
    }
#pragma unroll
    for (int t = 0; t < 4; ++t) {
        const int c = 2 * t + kg;
        bf16x8 a  = *(const bf16x8*)(myslab + 4096 + c * 512 + ((r ^ (c & 3)) * 16));
        bf16x8 w0 = *(const bf16x8*)&Wc1T[r * 144 + (4 + t) * 16 + kg * 8];
        bf16x8 w1 = *(const bf16x8*)&Wc1T[(r + 32) * 144 + (4 + t) * 16 + kg * 8];
        acc0 = __builtin_amdgcn_mfma_f32_32x32x16_bf16(a, w0, acc0, 0, 0, 0);
        acc1 = __builtin_amdgcn_mfma_f32_32x32x16_bf16(a, w1, acc1, 0, 0, 0);
    }
    {
        bf16x8 w0 = *(const bf16x8*)&Wc1T[r * 144 + 128 + kg * 8];
        bf16x8 w1 = *(const bf16x8*)&Wc1T[(r + 32) * 144 + 128 + kg * 8];
        acc0 = __builtin_amdgcn_mfma_f32_32x32x16_bf16(aa, w0, acc0, 0, 0, 0);
        acc1 = __builtin_amdgcn_mfma_f32_32x32x16_bf16(aa, w1, acc1, 0, 0, 0);
    }

    // epilogue 1: relu -> bf16 -> XOR-swizzled hid (src half, now dead)
#pragma unroll
    for (int reg = 0; reg < 16; ++reg) {
        const int row = (reg & 3) + 8 * (reg >> 2) + 4 * kg;
        const int sw  = (row & 7) << 4;
        float v0 = acc0[reg]; v0 = v0 > 0.f ? v0 : 0.f;
        float v1 = acc1[reg]; v1 = v1 > 0.f ? v1 : 0.f;
        hid[row * 64 + ((((r)      << 1) ^ sw) >> 1)] = f2bf(v0);
        hid[row * 64 + ((((r + 32) << 1) ^ sw) >> 1)] = f2bf(v1);
    }

    // layer 2
    const int sw2 = (r & 7) << 4;
    const float bias2 = (r < 5) ? bc2[r] : 0.f;
    f32x16 acc2;
#pragma unroll
    for (int i = 0; i < 16; ++i) acc2[i] = bias2;
#pragma unroll
    for (int t2 = 0; t2 < 4; ++t2) {
        const int boff = (t2 * 32 + kg * 16) ^ sw2;
        bf16x8 a  = *(const bf16x8*)((const char*)&hid[r * 64] + boff);
        bf16x8 bw = *(const bf16x8*)&Wc2T[r * 64 + t2 * 16 + kg * 8];
        acc2 = __builtin_amdgcn_mfma_f32_32x32x16_bf16(a, bw, acc2, 0, 0, 0);
    }

    // stores
#pragma unroll
    for (int reg = 0; reg < 16; ++reg) {
        const int row = (reg & 3) + 8 * (reg >> 2) + 4 * kg;
        const long eo = eb + row;
        if (r < 5 && eo < E) out[(size_t)eo * 5 + r] = acc2[reg];
    }
}

extern "C" void kernel_launch(void* const* d_in, const int* in_sizes, int n_in,
                              void* d_out, int out_size, void* d_ws, size_t ws_size,
                              hipStream_t stream)
{
    const float* x     = (const float*)d_in[0];
    const int*   ei    = (const int*)d_in[1];
    const float* eattr = (const float*)d_in[2];
    const float* W1    = (const float*)d_in[3];
    const float* b1    = (const float*)d_in[4];
    const float* W2    = (const float*)d_in[5];
    const float* b2    = (const float*)d_in[6];
    const float* Wc1   = (const float*)d_in[7];
    const float* bc1   = (const float*)d_in[8];
    const float* Wc2   = (const float*)d_in[9];
    const float* bc2   = (const float*)d_in[10];
    float* outp = (float*)d_out;

    const int N = in_sizes[0] / 32;
    const int E = in_sizes[1] / 2;

    // ---- carve workspace ----
    size_t off = 0;
    char* base = (char*)d_ws;
    auto carve = [&](size_t bytes) -> void* {
        void* p = base + off;
        off += (bytes + 255) & ~(size_t)255;
        return p;
    };
    int*   degcnt = (int*)carve((size_t)2 * N * 4);
    int*   cursor = degcnt + N;
    float* dinv   = (float*)carve((size_t)N * 4);
    int*   rs     = (int*)carve((size_t)(N + 1) * 4);
    int*   bsum   = (int*)carve(512 * 4);
    int*   boff   = (int*)carve(512 * 4);
    int*   col    = (int*)carve((size_t)E * 4);
    unsigned short* xs    = (unsigned short*)carve((size_t)N * 32 * 2);
    unsigned short* xagg  = (unsigned short*)carve((size_t)N * 32 * 2);
    unsigned short* h1s   = (unsigned short*)carve((size_t)N * 64 * 2);
    unsigned short* xagg2 = (unsigned short*)carve((size_t)N * 64 * 2);
    unsigned short* h2bf  = h1s;   // alias: h1s dead after k_agg64 reads it
    short* Wc1T   = (short*)carve(9216 * 2);
    short* Wc2T   = (short*)carve(2048 * 2);
    short* W2T    = (short*)carve(4096 * 2);
    short* W1T    = (short*)carve(2048 * 2);
    unsigned short* eabf = (unsigned short*)carve((size_t)E * 16 * 2);   // optional
    const bool use_abf = (off <= ws_size);
    (void)n_in; (void)out_size;

    const int NB = (N + 255) / 256;
    const int EB = (E + 255) / 256;
    const int NAX = (N + 15) / 16;       // agg_x: 16 nodes/block
    const int NA = (N + 7) / 8;          // agg64: 8 nodes/block
    const int NM = (N + 127) / 128;      // node MM: 128 nodes/block
    const int NT = (E + 127) / 128;      // edge-MLP: 128 edges/block

    hipMemsetAsync(degcnt, 0, (size_t)2 * N * 4, stream);

    k_prep<<<68, 256, 0, stream>>>(Wc1, Wc2, W2, W1, Wc1T, Wc2T, W2T, W1T);
    k_hist<<<EB, 256, 0, stream>>>(ei, degcnt, E);
    k_dinv_bsum<<<NB, 256, 0, stream>>>(degcnt, dinv, N, bsum);
    k_xs<<<(N * 16 + 255) / 256, 256, 0, stream>>>(x, dinv, xs, N);
    if (use_abf) k_ea<<<(int)(((long)E * 4 + 255) / 256), 256, 0, stream>>>(eattr, eabf, (long)E * 4);
    k_boff<<<1, 512, 0, stream>>>(bsum, NB, boff);
    k_rowstart<<<NB, 256, 0, stream>>>(degcnt, boff, rs, N, E);
    k_scatter<<<EB, 256, 0, stream>>>(ei, rs, cursor, col, E);

    // layer 1 (aggregate in x-space, then GEMM)
    k_agg_x<<<NAX, 256, 0, stream>>>(xs, dinv, rs, col, xagg, N);
    k_node1<<<NM, 256, 0, stream>>>(xagg, W1T, b1, dinv, h1s, N);
    // layer 2 (aggregate-first, then GEMM)
    k_agg64<<<NA, 256, 0, stream>>>(h1s, dinv, rs, col, xagg2, N);
    k_node2<<<NM, 256, 0, stream>>>(xagg2, W2T, b2, h2bf, N);
    // edge MLP
    if (use_abf)
        k_edge_mlp_mfma<1><<<NT, 256, 0, stream>>>(h2bf, eabf, ei, Wc1T, bc1, Wc2T, bc2, outp, E);
    else
        k_edge_mlp_mfma<0><<<NT, 256, 0, stream>>>(h2bf, eattr, ei, Wc1T, bc1, Wc2T, bc2, outp, E);
}

// Round 11
// 314.684 us; speedup vs baseline: 1.2927x; 1.2927x over previous
//
#include <hip/hip_runtime.h>
#include <hip/hip_bf16.h>

// ---------------------------------------------------------------------------
// EdgeClassifier: 2x GCNConv + edge MLP. All node intermediates bf16.
// CSR build via bucket sort (256 nodes/bucket) to kill write amplification:
//   bcount -> bscan -> binscatter (block-local LDS pre-sort, contiguous runs)
//   -> build (block per bucket: rs, col, dinv; col writes XCD-local)
// Layer 1 aggregates in x-space (64B rows); layer 2 aggregate-first.
// Edge MLP: coop full-line gathers + XOR-swizzled LDS slab, bf16 attr.
// ---------------------------------------------------------------------------

typedef __attribute__((ext_vector_type(8))) short  bf16x8;
typedef __attribute__((ext_vector_type(16))) float f32x16;

__device__ inline short f2bf(float f)
{
    union { float f; unsigned u; } v; v.f = f;
    unsigned r = v.u + 0x7fff + ((v.u >> 16) & 1);   // RNE
    return (short)(r >> 16);
}

__device__ inline float2 bfp2f(unsigned u)
{
    union { unsigned u; float f; } a, b;
    a.u = u << 16;
    b.u = u & 0xffff0000u;
    return make_float2(a.f, b.f);
}

__device__ inline unsigned packbf2(float a, float b)
{
    return (unsigned)(unsigned short)f2bf(a) | ((unsigned)(unsigned short)f2bf(b) << 16);
}

// ---------------- bucketed CSR build ----------------
// bucket = dst >> 8 (256 nodes per bucket)

__global__ __launch_bounds__(256) void k_bcount(const int* __restrict__ ei, int* __restrict__ bcnt, int E)
{
    __shared__ int h[512];
    for (int i = threadIdx.x; i < 512; i += 256) h[i] = 0;
    __syncthreads();
    for (long e = (long)blockIdx.x * 256 + threadIdx.x; e < E; e += (long)gridDim.x * 256)
        atomicAdd(&h[ei[E + e] >> 8], 1);
    __syncthreads();
    for (int i = threadIdx.x; i < 512; i += 256)
        if (h[i]) atomicAdd(&bcnt[i], h[i]);
}

__global__ __launch_bounds__(512) void k_bscan(const int* __restrict__ bcnt, int nbk, int* __restrict__ bstart)
{
    __shared__ int s[512];
    int t = threadIdx.x;
    int v = (t < nbk) ? bcnt[t] : 0;
    s[t] = v;
    __syncthreads();
    for (int o = 1; o < 512; o <<= 1) {
        int a = (t >= o) ? s[t - o] : 0;
        __syncthreads();
        s[t] += a;
        __syncthreads();
    }
    if (t < nbk) bstart[t + 1] = s[t];   // inclusive -> start[t+1]
    if (t == 0) bstart[0] = 0;
}

// block = 4096 edges; LDS counting pre-sort -> contiguous per-bucket runs in ebs
__global__ __launch_bounds__(256) void k_binscatter(const int* __restrict__ ei, const int* __restrict__ bstart,
                                                    int* __restrict__ bcur, int2* __restrict__ ebs, int E)
{
    __shared__ int cnt[512], gb[512];
    const int tid = threadIdx.x;
    for (int i = tid; i < 512; i += 256) cnt[i] = 0;
    __syncthreads();
    const int base = blockIdx.x * 4096;
    int d[16], lp[16];
#pragma unroll
    for (int i = 0; i < 16; ++i) {
        int e = base + i * 256 + tid;
        if (e < E) {
            d[i] = ei[E + e];
            lp[i] = atomicAdd(&cnt[d[i] >> 8], 1);
        } else d[i] = -1;
    }
    __syncthreads();
    for (int i = tid; i < 512; i += 256) gb[i] = cnt[i] ? atomicAdd(&bcur[i], cnt[i]) : 0;
    __syncthreads();
#pragma unroll
    for (int i = 0; i < 16; ++i) {
        if (d[i] >= 0) {
            int e = base + i * 256 + tid;
            int b = d[i] >> 8;
            int2 p;
            p.x = ei[e];          // src
            p.y = d[i];           // dst
            ebs[(size_t)bstart[b] + gb[b] + lp[i]] = p;
        }
    }
}

// block per bucket: per-node counts -> rs, dinv; col writes confined to bucket window
__global__ __launch_bounds__(256) void k_build(const int2* __restrict__ ebs, const int* __restrict__ bstart,
                                               int* __restrict__ rs, int* __restrict__ col,
                                               float* __restrict__ dinv, int N, int E)
{
    __shared__ int cnt[256], lstart[256], cnt2[256];
    const int b = blockIdx.x;
    const int base = b << 8;
    const int tid = threadIdx.x;
    cnt[tid] = 0; cnt2[tid] = 0;
    __syncthreads();
    const int s0 = bstart[b], s1 = bstart[b + 1];
    for (int i = s0 + tid; i < s1; i += 256) atomicAdd(&cnt[ebs[i].y - base], 1);
    __syncthreads();
    const int v = cnt[tid];
    lstart[tid] = v;
    __syncthreads();
    for (int o = 1; o < 256; o <<= 1) {
        int a = (tid >= o) ? lstart[tid - o] : 0;
        __syncthreads();
        lstart[tid] += a;
        __syncthreads();
    }
    const int node = base + tid;
    if (node < N) {
        rs[node] = s0 + lstart[tid] - v;          // exclusive start
        dinv[node] = rsqrtf((float)(v + 1));      // +1 self loop
    }
    if (b == 0 && tid == 0) rs[N] = E;
    __syncthreads();
    for (int i = s0 + tid; i < s1; i += 256) {
        int2 p = ebs[i];
        int ln = p.y - base;
        int pos = atomicAdd(&cnt2[ln], 1);
        col[s0 + (lstart[ln] - cnt[ln]) + pos] = p.x;
    }
}

// ---------------- weight prep (all bf16, transposed) ----------------
__global__ __launch_bounds__(256) void k_prep(const float* __restrict__ Wc1, const float* __restrict__ Wc2,
                                              const float* __restrict__ W2, const float* __restrict__ W1,
                                              short* __restrict__ Wc1T, short* __restrict__ Wc2T,
                                              short* __restrict__ W2T, short* __restrict__ W1T)
{
    int t = blockIdx.x * 256 + threadIdx.x;
    if (t < 9216) {
        int j = t / 144, k = t - j * 144;
        Wc1T[t] = f2bf(Wc1[k * 64 + j]);
    } else if (t < 11264) {
        int u = t - 9216;
        int rr = u / 64, k = u - rr * 64;
        Wc2T[u] = (rr < 5) ? f2bf(Wc2[k * 5 + rr]) : (short)0;
    } else if (t < 15360) {
        int u = t - 11264;
        int j = u / 64, k = u - j * 64;
        W2T[u] = f2bf(W2[k * 64 + j]);
    } else if (t < 17408) {
        int u = t - 15360;
        int j = u / 32, k = u - j * 32;
        W1T[u] = f2bf(W1[k * 64 + j]);
    }
}

// ---------------- xs = bf16(x * dinv)  (N x 32) ----------------
__global__ __launch_bounds__(256) void k_xs(const float* __restrict__ x, const float* __restrict__ dinv,
                                            unsigned short* __restrict__ xs, int n)
{
    int id = blockIdx.x * 256 + threadIdx.x;
    int v = id >> 4, l = id & 15;
    if (v >= n) return;
    float2 xv = *(const float2*)&x[(size_t)v * 32 + l * 2];
    float dv = dinv[v];
    *(unsigned*)(xs + (size_t)v * 32 + l * 2) = packbf2(xv.x * dv, xv.y * dv);
}

// ---------------- eattr -> bf16 ----------------
__global__ __launch_bounds__(256) void k_ea(const float* __restrict__ ea, unsigned short* __restrict__ eabf, long n4)
{
    long id = (long)blockIdx.x * 256 + threadIdx.x;
    if (id >= n4) return;
    float4 v = *(const float4*)&ea[id * 4];
    short4 o;
    o.x = f2bf(v.x); o.y = f2bf(v.y); o.z = f2bf(v.z); o.w = f2bf(v.w);
    *(short4*)&eabf[id * 4] = o;
}

// ---------------- x-space aggregation (16 lanes/node, 64B rows) ----------------
__global__ __launch_bounds__(256) void k_agg_x(const unsigned short* __restrict__ xs,
                                               const float* __restrict__ dinv,
                                               const int* __restrict__ rs, const int* __restrict__ col,
                                               unsigned short* __restrict__ xagg, int n)
{
    const int tid = threadIdx.x;
    const int l   = tid & 15;
    const int v   = blockIdx.x * 16 + (tid >> 4);
    if (v >= n) return;

    float2 acc = bfp2f(*(const unsigned*)(xs + (size_t)v * 32 + l * 2));
    int i = rs[v];
    const int end = rs[v + 1];
    for (; i + 8 <= end; i += 8) {
        int c0 = col[i],     c1 = col[i + 1], c2 = col[i + 2], c3 = col[i + 3];
        int c4 = col[i + 4], c5 = col[i + 5], c6 = col[i + 6], c7 = col[i + 7];
        unsigned u0 = *(const unsigned*)(xs + (size_t)c0 * 32 + l * 2);
        unsigned u1 = *(const unsigned*)(xs + (size_t)c1 * 32 + l * 2);
        unsigned u2 = *(const unsigned*)(xs + (size_t)c2 * 32 + l * 2);
        unsigned u3 = *(const unsigned*)(xs + (size_t)c3 * 32 + l * 2);
        unsigned u4 = *(const unsigned*)(xs + (size_t)c4 * 32 + l * 2);
        unsigned u5 = *(const unsigned*)(xs + (size_t)c5 * 32 + l * 2);
        unsigned u6 = *(const unsigned*)(xs + (size_t)c6 * 32 + l * 2);
        unsigned u7 = *(const unsigned*)(xs + (size_t)c7 * 32 + l * 2);
        float2 a0 = bfp2f(u0), a1 = bfp2f(u1), a2 = bfp2f(u2), a3 = bfp2f(u3);
        float2 a4 = bfp2f(u4), a5 = bfp2f(u5), a6 = bfp2f(u6), a7 = bfp2f(u7);
        acc.x += (a0.x + a1.x) + (a2.x + a3.x) + (a4.x + a5.x) + (a6.x + a7.x);
        acc.y += (a0.y + a1.y) + (a2.y + a3.y) + (a4.y + a5.y) + (a6.y + a7.y);
    }
    for (; i < end; ++i) {
        float2 a = bfp2f(*(const unsigned*)(xs + (size_t)col[i] * 32 + l * 2));
        acc.x += a.x; acc.y += a.y;
    }
    const float dv = dinv[v];
    *(unsigned*)(xagg + (size_t)v * 32 + l * 2) = packbf2(dv * acc.x, dv * acc.y);
}

// ---------------- 64-dim aggregation ----------------
__global__ __launch_bounds__(256) void k_agg64(const unsigned short* __restrict__ hsc,
                                               const float* __restrict__ dinv,
                                               const int* __restrict__ rs, const int* __restrict__ col,
                                               unsigned short* __restrict__ out, int n)
{
    const int tid = threadIdx.x;
    const int l   = tid & 31;
    const int v   = blockIdx.x * 8 + (tid >> 5);
    if (v >= n) return;

    float2 acc = bfp2f(*(const unsigned*)(hsc + (size_t)v * 64 + l * 2));
    int i = rs[v];
    const int end = rs[v + 1];
    for (; i + 8 <= end; i += 8) {
        int c0 = col[i],     c1 = col[i + 1], c2 = col[i + 2], c3 = col[i + 3];
        int c4 = col[i + 4], c5 = col[i + 5], c6 = col[i + 6], c7 = col[i + 7];
        unsigned u0 = *(const unsigned*)(hsc + (size_t)c0 * 64 + l * 2);
        unsigned u1 = *(const unsigned*)(hsc + (size_t)c1 * 64 + l * 2);
        unsigned u2 = *(const unsigned*)(hsc + (size_t)c2 * 64 + l * 2);
        unsigned u3 = *(const unsigned*)(hsc + (size_t)c3 * 64 + l * 2);
        unsigned u4 = *(const unsigned*)(hsc + (size_t)c4 * 64 + l * 2);
        unsigned u5 = *(const unsigned*)(hsc + (size_t)c5 * 64 + l * 2);
        unsigned u6 = *(const unsigned*)(hsc + (size_t)c6 * 64 + l * 2);
        unsigned u7 = *(const unsigned*)(hsc + (size_t)c7 * 64 + l * 2);
        float2 a0 = bfp2f(u0), a1 = bfp2f(u1), a2 = bfp2f(u2), a3 = bfp2f(u3);
        float2 a4 = bfp2f(u4), a5 = bfp2f(u5), a6 = bfp2f(u6), a7 = bfp2f(u7);
        acc.x += (a0.x + a1.x) + (a2.x + a3.x) + (a4.x + a5.x) + (a6.x + a7.x);
        acc.y += (a0.y + a1.y) + (a2.y + a3.y) + (a4.y + a5.y) + (a6.y + a7.y);
    }
    for (; i < end; ++i) {
        float2 a = bfp2f(*(const unsigned*)(hsc + (size_t)col[i] * 64 + l * 2));
        acc.x += a.x; acc.y += a.y;
    }
    const float dv = dinv[v];
    *(unsigned*)(out + (size_t)v * 64 + l * 2) = packbf2(dv * acc.x, dv * acc.y);
}

// ---------------- node1: h1s = relu(xagg @ W1 + b1) * dinv ----------------
__global__ __launch_bounds__(256) void k_node1(const unsigned short* __restrict__ xagg,
                                               const short* __restrict__ W1T,
                                               const float* __restrict__ b1, const float* __restrict__ dinv,
                                               unsigned short* __restrict__ h1s, int n)
{
    const int tid = threadIdx.x;
    const int w = tid >> 6, lane = tid & 63, r = lane & 31, kg = lane >> 5;
    const int nb = blockIdx.x * 128 + w * 32;

    bf16x8 a0[2], a1[2];
#pragma unroll
    for (int t = 0; t < 2; ++t) {
        a0[t] = *(const bf16x8*)&W1T[r * 32 + t * 16 + kg * 8];
        a1[t] = *(const bf16x8*)&W1T[(r + 32) * 32 + t * 16 + kg * 8];
    }

    int row = nb + r;
    if (row >= n) row = n - 1;
    f32x16 acc0 = {0.f}, acc1 = {0.f};
#pragma unroll
    for (int t = 0; t < 2; ++t) {
        bf16x8 b = *(const bf16x8*)&xagg[(size_t)row * 32 + t * 16 + kg * 8];
        acc0 = __builtin_amdgcn_mfma_f32_32x32x16_bf16(a0[t], b, acc0, 0, 0, 0);
        acc1 = __builtin_amdgcn_mfma_f32_32x32x16_bf16(a1[t], b, acc1, 0, 0, 0);
    }

    const int node = nb + r;
    if (node < n) {
        const float dv = dinv[node];
#pragma unroll
        for (int q = 0; q < 4; ++q) {
            const int j0 = 8 * q + 4 * kg;
            float4 bA = *(const float4*)&b1[j0];
            float4 bB = *(const float4*)&b1[j0 + 32];
            short4 s0, s1;
            float t0, t1;
            t0 = acc0[4 * q]     + bA.x; t0 = t0 > 0.f ? t0 : 0.f; s0.x = f2bf(t0 * dv);
            t0 = acc0[4 * q + 1] + bA.y; t0 = t0 > 0.f ? t0 : 0.f; s0.y = f2bf(t0 * dv);
            t0 = acc0[4 * q + 2] + bA.z; t0 = t0 > 0.f ? t0 : 0.f; s0.z = f2bf(t0 * dv);
            t0 = acc0[4 * q + 3] + bA.w; t0 = t0 > 0.f ? t0 : 0.f; s0.w = f2bf(t0 * dv);
            t1 = acc1[4 * q]     + bB.x; t1 = t1 > 0.f ? t1 : 0.f; s1.x = f2bf(t1 * dv);
            t1 = acc1[4 * q + 1] + bB.y; t1 = t1 > 0.f ? t1 : 0.f; s1.y = f2bf(t1 * dv);
            t1 = acc1[4 * q + 2] + bB.z; t1 = t1 > 0.f ? t1 : 0.f; s1.z = f2bf(t1 * dv);
            t1 = acc1[4 * q + 3] + bB.w; t1 = t1 > 0.f ? t1 : 0.f; s1.w = f2bf(t1 * dv);
            *(short4*)&h1s[(size_t)node * 64 + j0]      = s0;
            *(short4*)&h1s[(size_t)node * 64 + j0 + 32] = s1;
        }
    }
}

// ---------------- node2: h2 = xagg2 @ W2 + b2 ----------------
__global__ __launch_bounds__(256) void k_node2(const unsigned short* __restrict__ xagg2,
                                               const short* __restrict__ W2T,
                                               const float* __restrict__ b2,
                                               unsigned short* __restrict__ h2, int n)
{
    const int tid = threadIdx.x;
    const int w = tid >> 6, lane = tid & 63, r = lane & 31, kg = lane >> 5;
    const int nb = blockIdx.x * 128 + w * 32;

    bf16x8 a0[4], a1[4];
#pragma unroll
    for (int t = 0; t < 4; ++t) {
        a0[t] = *(const bf16x8*)&W2T[r * 64 + t * 16 + kg * 8];
        a1[t] = *(const bf16x8*)&W2T[(r + 32) * 64 + t * 16 + kg * 8];
    }

    int row = nb + r;
    if (row >= n) row = n - 1;
    f32x16 acc0 = {0.f}, acc1 = {0.f};
#pragma unroll
    for (int t = 0; t < 4; ++t) {
        bf16x8 b = *(const bf16x8*)&xagg2[(size_t)row * 64 + t * 16 + kg * 8];
        acc0 = __builtin_amdgcn_mfma_f32_32x32x16_bf16(a0[t], b, acc0, 0, 0, 0);
        acc1 = __builtin_amdgcn_mfma_f32_32x32x16_bf16(a1[t], b, acc1, 0, 0, 0);
    }

    const int node = nb + r;
    if (node < n) {
#pragma unroll
        for (int q = 0; q < 4; ++q) {
            const int j0 = 8 * q + 4 * kg;
            float4 bA = *(const float4*)&b2[j0];
            float4 bB = *(const float4*)&b2[j0 + 32];
            short4 s0, s1;
            s0.x = f2bf(acc0[4 * q]     + bA.x); s0.y = f2bf(acc0[4 * q + 1] + bA.y);
            s0.z = f2bf(acc0[4 * q + 2] + bA.z); s0.w = f2bf(acc0[4 * q + 3] + bA.w);
            s1.x = f2bf(acc1[4 * q]     + bB.x); s1.y = f2bf(acc1[4 * q + 1] + bB.y);
            s1.z = f2bf(acc1[4 * q + 2] + bB.z); s1.w = f2bf(acc1[4 * q + 3] + bB.w);
            *(short4*)&h2[(size_t)node * 64 + j0]      = s0;
            *(short4*)&h2[(size_t)node * 64 + j0 + 32] = s1;
        }
    }
}

// ---------------- MFMA edge MLP, coop gathers + XOR-swizzled slab ----------------
template <int ABF>
__global__ __launch_bounds__(256) void k_edge_mlp_mfma(
    const unsigned short* __restrict__ h2bf, const void* __restrict__ eattr,
    const int* __restrict__ ei,
    const short* __restrict__ Wc1T, const float* __restrict__ bc1,
    const short* __restrict__ Wc2T, const float* __restrict__ bc2,
    float* __restrict__ out, int E)
{
    __shared__ char slab[4 * 8192];   // 32 KB

    const int tid = threadIdx.x;
    const int w = tid >> 6, lane = tid & 63, r = lane & 31, kg = lane >> 5;
    const int q = lane & 3, sr = lane >> 2;

    char* myslab = slab + w * 8192;
    short* hid = (short*)myslab;

    const long eb = (long)blockIdx.x * 128 + w * 32;
    long ecl = eb + r; if (ecl >= E) ecl = E - 1;
    const int ns = ei[ecl];
    const int nd = ei[E + ecl];

    bf16x8 aa;
    if (ABF) {
        aa = *(const bf16x8*)((const unsigned short*)eattr + (size_t)ecl * 16 + kg * 8);
    } else {
        const float* arow = (const float*)eattr + (size_t)ecl * 16;
        float4 alo = *(const float4*)&arow[kg * 8];
        float4 ahi = *(const float4*)&arow[kg * 8 + 4];
        aa[0] = f2bf(alo.x); aa[1] = f2bf(alo.y); aa[2] = f2bf(alo.z); aa[3] = f2bf(alo.w);
        aa[4] = f2bf(ahi.x); aa[5] = f2bf(ahi.y); aa[6] = f2bf(ahi.z); aa[7] = f2bf(ahi.w);
    }

    {
        int n0 = __shfl(ns, sr);
        int n1 = __shfl(ns, 16 + sr);
        int m0 = __shfl(nd, sr);
        int m1 = __shfl(nd, 16 + sr);
        int4 s0 = *(const int4*)&h2bf[(size_t)n0 * 64 + q * 8];
        int4 s1 = *(const int4*)&h2bf[(size_t)n0 * 64 + 32 + q * 8];
        int4 s2 = *(const int4*)&h2bf[(size_t)n1 * 64 + q * 8];
        int4 s3 = *(const int4*)&h2bf[(size_t)n1 * 64 + 32 + q * 8];
        int4 d0 = *(const int4*)&h2bf[(size_t)m0 * 64 + q * 8];
        int4 d1 = *(const int4*)&h2bf[(size_t)m0 * 64 + 32 + q * 8];
        int4 d2 = *(const int4*)&h2bf[(size_t)m1 * 64 + q * 8];
        int4 d3 = *(const int4*)&h2bf[(size_t)m1 * 64 + 32 + q * 8];
        const int x0 = (sr ^ q) * 16, x1 = (16 + (sr ^ q)) * 16;
        *(int4*)(myslab + q * 512 + x0)              = s0;
        *(int4*)(myslab + (4 + q) * 512 + x0)        = s1;
        *(int4*)(myslab + q * 512 + x1)              = s2;
        *(int4*)(myslab + (4 + q) * 512 + x1)        = s3;
        *(int4*)(myslab + 4096 + q * 512 + x0)       = d0;
        *(int4*)(myslab + 4096 + (4 + q) * 512 + x0) = d1;
        *(int4*)(myslab + 4096 + q * 512 + x1)       = d2;
        *(int4*)(myslab + 4096 + (4 + q) * 512 + x1) = d3;
    }

    f32x16 acc0, acc1;
    const float bias0 = bc1[r], bias1 = bc1[r + 32];
#pragma unroll
    for (int i = 0; i < 16; ++i) { acc0[i] = bias0; acc1[i] = bias1; }

#pragma unroll
    for (int t = 0; t < 4; ++t) {
        const int c = 2 * t + kg;
        bf16x8 a  = *(const bf16x8*)(myslab + c * 512 + ((r ^ (c & 3)) * 16));
        bf16x8 w0 = *(const bf16x8*)&Wc1T[r * 144 + t * 16 + kg * 8];
        bf16x8 w1 = *(const bf16x8*)&Wc1T[(r + 32) * 144 + t * 16 + kg * 8];
        acc0 = __builtin_amdgcn_mfma_f32_32x32x16_bf16(a, w0, acc0, 0, 0, 0);
        acc1 = __builtin_amdgcn_mfma_f32_32x32x16_bf16(a, w1, acc1, 0, 0, 0);
    }
#pragma unroll
    for (int t = 0; t < 4; ++t) {
        const int c = 2 * t + kg;
        bf16x8 a  = *(const bf16x8*)(myslab + 4096 + c * 512 + ((r ^ (c & 3)) * 16));
        bf16x8 w0 = *(const bf16x8*)&Wc1T[r * 144 + (4 + t) * 16 + kg * 8];
        bf16x8 w1 = *(const bf16x8*)&Wc1T[(r + 32) * 144 + (4 + t) * 16 + kg * 8];
        acc0 = __builtin_amdgcn_mfma_f32_32x32x16_bf16(a, w0, acc0, 0, 0, 0);
        acc1 = __builtin_amdgcn_mfma_f32_32x32x16_bf16(a, w1, acc1, 0, 0, 0);
    }
    {
        bf16x8 w0 = *(const bf16x8*)&Wc1T[r * 144 + 128 + kg * 8];
        bf16x8 w1 = *(const bf16x8*)&Wc1T[(r + 32) * 144 + 128 + kg * 8];
        acc0 = __builtin_amdgcn_mfma_f32_32x32x16_bf16(aa, w0, acc0, 0, 0, 0);
        acc1 = __builtin_amdgcn_mfma_f32_32x32x16_bf16(aa, w1, acc1, 0, 0, 0);
    }

#pragma unroll
    for (int reg = 0; reg < 16; ++reg) {
        const int row = (reg & 3) + 8 * (reg >> 2) + 4 * kg;
        const int sw  = (row & 7) << 4;
        float v0 = acc0[reg]; v0 = v0 > 0.f ? v0 : 0.f;
        float v1 = acc1[reg]; v1 = v1 > 0.f ? v1 : 0.f;
        hid[row * 64 + ((((r)      << 1) ^ sw) >> 1)] = f2bf(v0);
        hid[row * 64 + ((((r + 32) << 1) ^ sw) >> 1)] = f2bf(v1);
    }

    const int sw2 = (r & 7) << 4;
    const float bias2 = (r < 5) ? bc2[r] : 0.f;
    f32x16 acc2;
#pragma unroll
    for (int i = 0; i < 16; ++i) acc2[i] = bias2;
#pragma unroll
    for (int t2 = 0; t2 < 4; ++t2) {
        const int boff = (t2 * 32 + kg * 16) ^ sw2;
        bf16x8 a  = *(const bf16x8*)((const char*)&hid[r * 64] + boff);
        bf16x8 bw = *(const bf16x8*)&Wc2T[r * 64 + t2 * 16 + kg * 8];
        acc2 = __builtin_amdgcn_mfma_f32_32x32x16_bf16(a, bw, acc2, 0, 0, 0);
    }

#pragma unroll
    for (int reg = 0; reg < 16; ++reg) {
        const int row = (reg & 3) + 8 * (reg >> 2) + 4 * kg;
        const long eo = eb + row;
        if (r < 5 && eo < E) out[(size_t)eo * 5 + r] = acc2[reg];
    }
}

extern "C" void kernel_launch(void* const* d_in, const int* in_sizes, int n_in,
                              void* d_out, int out_size, void* d_ws, size_t ws_size,
                              hipStream_t stream)
{
    const float* x     = (const float*)d_in[0];
    const int*   ei    = (const int*)d_in[1];
    const float* eattr = (const float*)d_in[2];
    const float* W1    = (const float*)d_in[3];
    const float* b1    = (const float*)d_in[4];
    const float* W2    = (const float*)d_in[5];
    const float* b2    = (const float*)d_in[6];
    const float* Wc1   = (const float*)d_in[7];
    const float* bc1   = (const float*)d_in[8];
    const float* Wc2   = (const float*)d_in[9];
    const float* bc2   = (const float*)d_in[10];
    float* outp = (float*)d_out;

    const int N = in_sizes[0] / 32;
    const int E = in_sizes[1] / 2;
    const int nbk = (N + 255) >> 8;      // buckets of 256 nodes (<=512)

    // ---- carve workspace ----
    size_t off = 0;
    char* base = (char*)d_ws;
    auto carve = [&](size_t bytes) -> void* {
        void* p = base + off;
        off += (bytes + 255) & ~(size_t)255;
        return p;
    };
    int*   bcnt   = (int*)carve(1024 * 4);           // bcnt + bcur adjacent
    int*   bcur   = bcnt + 512;
    int*   bstart = (int*)carve(520 * 4);
    float* dinv   = (float*)carve((size_t)N * 4);
    int*   rs     = (int*)carve((size_t)(N + 1) * 4);
    int*   col    = (int*)carve((size_t)E * 4);
    int2*  ebs    = (int2*)carve((size_t)E * 8);
    unsigned short* xs    = (unsigned short*)carve((size_t)N * 32 * 2);
    unsigned short* xagg  = (unsigned short*)carve((size_t)N * 32 * 2);
    unsigned short* h1s   = (unsigned short*)carve((size_t)N * 64 * 2);
    unsigned short* xagg2 = (unsigned short*)carve((size_t)N * 64 * 2);
    unsigned short* h2bf  = h1s;   // alias: h1s dead after k_agg64 reads it
    short* Wc1T   = (short*)carve(9216 * 2);
    short* Wc2T   = (short*)carve(2048 * 2);
    short* W2T    = (short*)carve(4096 * 2);
    short* W1T    = (short*)carve(2048 * 2);
    unsigned short* eabf = (unsigned short*)carve((size_t)E * 16 * 2);   // optional
    const bool use_abf = (off <= ws_size);
    (void)n_in; (void)out_size;

    const int NAX = (N + 15) / 16;       // agg_x: 16 nodes/block
    const int NA = (N + 7) / 8;          // agg64: 8 nodes/block
    const int NM = (N + 127) / 128;      // node MM: 128 nodes/block
    const int NT = (E + 127) / 128;      // edge-MLP: 128 edges/block
    const int NSC = (E + 4095) / 4096;   // binscatter chunks

    hipMemsetAsync(bcnt, 0, 1024 * 4, stream);

    k_prep<<<68, 256, 0, stream>>>(Wc1, Wc2, W2, W1, Wc1T, Wc2T, W2T, W1T);
    if (use_abf) k_ea<<<(int)(((long)E * 4 + 255) / 256), 256, 0, stream>>>(eattr, eabf, (long)E * 4);

    // ---- bucketed CSR build ----
    k_bcount<<<1024, 256, 0, stream>>>(ei, bcnt, E);
    k_bscan<<<1, 512, 0, stream>>>(bcnt, nbk, bstart);
    k_binscatter<<<NSC, 256, 0, stream>>>(ei, bstart, bcur, ebs, E);
    k_build<<<nbk, 256, 0, stream>>>(ebs, bstart, rs, col, dinv, N, E);

    // ---- GCN layers ----
    k_xs<<<(N * 16 + 255) / 256, 256, 0, stream>>>(x, dinv, xs, N);
    k_agg_x<<<NAX, 256, 0, stream>>>(xs, dinv, rs, col, xagg, N);
    k_node1<<<NM, 256, 0, stream>>>(xagg, W1T, b1, dinv, h1s, N);
    k_agg64<<<NA, 256, 0, stream>>>(h1s, dinv, rs, col, xagg2, N);
    k_node2<<<NM, 256, 0, stream>>>(xagg2, W2T, b2, h2bf, N);

    // ---- edge MLP ----
    if (use_abf)
        k_edge_mlp_mfma<1><<<NT, 256, 0, stream>>>(h2bf, eabf, ei, Wc1T, bc1, Wc2T, bc2, outp, E);
    else
        k_edge_mlp_mfma<0><<<NT, 256, 0, stream>>>(h2bf, eattr, ei, Wc1T, bc1, Wc2T, bc2, outp, E);
}

// Round 12
// 287.484 us; speedup vs baseline: 1.4150x; 1.0946x over previous
//
#include <hip/hip_runtime.h>
#include <hip/hip_bf16.h>

// ---------------------------------------------------------------------------
// EdgeClassifier: 2x GCNConv + edge MLP. All node intermediates bf16.
// CSR build via bucket sort (256 nodes/bucket): bcount -> bscan -> binscatter
//   -> build (rs, col, dinv, and xs=bf16(x*dinv) fused).
// Layer 1 aggregates in x-space (64B rows, 1 instr/row); layer 2 agg-first
//   (128B rows, 1 instr/row). node GEMMs via MFMA (swapped operands).
// Edge MLP: coop full-line gathers + XOR-swizzled slab; hid stored as packed
//   u32 pairs with k-permuted Wc2T; attr read directly as f32.
// ---------------------------------------------------------------------------

typedef __attribute__((ext_vector_type(8))) short  bf16x8;
typedef __attribute__((ext_vector_type(16))) float f32x16;

__device__ inline short f2bf(float f)
{
    union { float f; unsigned u; } v; v.f = f;
    unsigned r = v.u + 0x7fff + ((v.u >> 16) & 1);   // RNE
    return (short)(r >> 16);
}

__device__ inline float2 bfp2f(unsigned u)
{
    union { unsigned u; float f; } a, b;
    a.u = u << 16;
    b.u = u & 0xffff0000u;
    return make_float2(a.f, b.f);
}

__device__ inline unsigned packbf2(float a, float b)
{
    return (unsigned)(unsigned short)f2bf(a) | ((unsigned)(unsigned short)f2bf(b) << 16);
}

// ---------------- bucketed CSR build (bucket = dst >> 8) ----------------
__global__ __launch_bounds__(256) void k_bcount(const int* __restrict__ ei, int* __restrict__ bcnt, int E)
{
    __shared__ int h[512];
    for (int i = threadIdx.x; i < 512; i += 256) h[i] = 0;
    __syncthreads();
    for (long e = (long)blockIdx.x * 256 + threadIdx.x; e < E; e += (long)gridDim.x * 256)
        atomicAdd(&h[ei[E + e] >> 8], 1);
    __syncthreads();
    for (int i = threadIdx.x; i < 512; i += 256)
        if (h[i]) atomicAdd(&bcnt[i], h[i]);
}

__global__ __launch_bounds__(512) void k_bscan(const int* __restrict__ bcnt, int nbk, int* __restrict__ bstart)
{
    __shared__ int s[512];
    int t = threadIdx.x;
    int v = (t < nbk) ? bcnt[t] : 0;
    s[t] = v;
    __syncthreads();
    for (int o = 1; o < 512; o <<= 1) {
        int a = (t >= o) ? s[t - o] : 0;
        __syncthreads();
        s[t] += a;
        __syncthreads();
    }
    if (t < nbk) bstart[t + 1] = s[t];
    if (t == 0) bstart[0] = 0;
}

__global__ __launch_bounds__(256) void k_binscatter(const int* __restrict__ ei, const int* __restrict__ bstart,
                                                    int* __restrict__ bcur, int2* __restrict__ ebs, int E)
{
    __shared__ int cnt[512], gb[512];
    const int tid = threadIdx.x;
    for (int i = tid; i < 512; i += 256) cnt[i] = 0;
    __syncthreads();
    const int base = blockIdx.x * 4096;
    int d[16], lp[16];
#pragma unroll
    for (int i = 0; i < 16; ++i) {
        int e = base + i * 256 + tid;
        if (e < E) {
            d[i] = ei[E + e];
            lp[i] = atomicAdd(&cnt[d[i] >> 8], 1);
        } else d[i] = -1;
    }
    __syncthreads();
    for (int i = tid; i < 512; i += 256) gb[i] = cnt[i] ? atomicAdd(&bcur[i], cnt[i]) : 0;
    __syncthreads();
#pragma unroll
    for (int i = 0; i < 16; ++i) {
        if (d[i] >= 0) {
            int e = base + i * 256 + tid;
            int b = d[i] >> 8;
            int2 p;
            p.x = ei[e];
            p.y = d[i];
            ebs[(size_t)bstart[b] + gb[b] + lp[i]] = p;
        }
    }
}

// block per bucket: rs, col, dinv + fused xs = bf16(x*dinv)
__global__ __launch_bounds__(256) void k_build(const int2* __restrict__ ebs, const int* __restrict__ bstart,
                                               int* __restrict__ rs, int* __restrict__ col,
                                               float* __restrict__ dinv,
                                               const float* __restrict__ x, unsigned short* __restrict__ xs,
                                               int N, int E)
{
    __shared__ int cnt[256], lstart[256], cnt2[256];
    const int b = blockIdx.x;
    const int base = b << 8;
    const int tid = threadIdx.x;
    cnt[tid] = 0; cnt2[tid] = 0;
    __syncthreads();
    const int s0 = bstart[b], s1 = bstart[b + 1];
    for (int i = s0 + tid; i < s1; i += 256) atomicAdd(&cnt[ebs[i].y - base], 1);
    __syncthreads();
    const int v = cnt[tid];
    lstart[tid] = v;
    __syncthreads();
    for (int o = 1; o < 256; o <<= 1) {
        int a = (tid >= o) ? lstart[tid - o] : 0;
        __syncthreads();
        lstart[tid] += a;
        __syncthreads();
    }
    const int node = base + tid;
    if (node < N) {
        rs[node] = s0 + lstart[tid] - v;
        dinv[node] = rsqrtf((float)(v + 1));
    }
    if (b == 0 && tid == 0) rs[N] = E;
    __syncthreads();
    for (int i = s0 + tid; i < s1; i += 256) {
        int2 p = ebs[i];
        int ln = p.y - base;
        int pos = atomicAdd(&cnt2[ln], 1);
        col[s0 + (lstart[ln] - cnt[ln]) + pos] = p.x;
    }
    // fused xs: 256 nodes x 16 float2 pairs = 4096 items
#pragma unroll
    for (int i = 0; i < 16; ++i) {
        int id = i * 256 + tid;
        int ni = id >> 4, pr = id & 15;
        int nd = base + ni;
        if (nd < N) {
            float dv = rsqrtf((float)(cnt[ni] + 1));
            float2 xv = *(const float2*)&x[(size_t)nd * 32 + pr * 2];
            *(unsigned*)(xs + (size_t)nd * 32 + pr * 2) = packbf2(xv.x * dv, xv.y * dv);
        }
    }
}

// ---------------- weight prep (bf16, transposed; Wc2T k-permuted) ----------------
// perm: short-position p within a hid row holds original k = (p>>1) + 32*(p&1)
__global__ __launch_bounds__(256) void k_prep(const float* __restrict__ Wc1, const float* __restrict__ Wc2,
                                              const float* __restrict__ W2, const float* __restrict__ W1,
                                              short* __restrict__ Wc1T, short* __restrict__ Wc2T,
                                              short* __restrict__ W2T, short* __restrict__ W1T)
{
    int t = blockIdx.x * 256 + threadIdx.x;
    if (t < 9216) {
        int j = t / 144, k = t - j * 144;
        Wc1T[t] = f2bf(Wc1[k * 64 + j]);
    } else if (t < 11264) {
        int u = t - 9216;
        int rr = u / 64, p = u - rr * 64;
        int k = (p >> 1) + ((p & 1) << 5);   // k-permutation for packed hid
        Wc2T[u] = (rr < 5) ? f2bf(Wc2[k * 5 + rr]) : (short)0;
    } else if (t < 15360) {
        int u = t - 11264;
        int j = u / 64, k = u - j * 64;
        W2T[u] = f2bf(W2[k * 64 + j]);
    } else if (t < 17408) {
        int u = t - 15360;
        int j = u / 32, k = u - j * 32;
        W1T[u] = f2bf(W1[k * 64 + j]);
    }
}

// ---------------- x-space aggregation: 8 lanes/node, uint2 = full 64B row ----------------
__global__ __launch_bounds__(256) void k_agg_x(const unsigned short* __restrict__ xs,
                                               const float* __restrict__ dinv,
                                               const int* __restrict__ rs, const int* __restrict__ col,
                                               unsigned short* __restrict__ xagg, int n)
{
    const int tid = threadIdx.x;
    const int l   = tid & 7;                  // 4 channels per lane
    const int v   = blockIdx.x * 32 + (tid >> 3);
    if (v >= n) return;

    uint2 sv = *(const uint2*)(xs + (size_t)v * 32 + l * 4);
    float2 aL = bfp2f(sv.x), aH = bfp2f(sv.y);
    int i = rs[v];
    const int end = rs[v + 1];
    for (; i + 8 <= end; i += 8) {
        int c0 = col[i],     c1 = col[i + 1], c2 = col[i + 2], c3 = col[i + 3];
        int c4 = col[i + 4], c5 = col[i + 5], c6 = col[i + 6], c7 = col[i + 7];
        uint2 u0 = *(const uint2*)(xs + (size_t)c0 * 32 + l * 4);
        uint2 u1 = *(const uint2*)(xs + (size_t)c1 * 32 + l * 4);
        uint2 u2 = *(const uint2*)(xs + (size_t)c2 * 32 + l * 4);
        uint2 u3 = *(const uint2*)(xs + (size_t)c3 * 32 + l * 4);
        uint2 u4 = *(const uint2*)(xs + (size_t)c4 * 32 + l * 4);
        uint2 u5 = *(const uint2*)(xs + (size_t)c5 * 32 + l * 4);
        uint2 u6 = *(const uint2*)(xs + (size_t)c6 * 32 + l * 4);
        uint2 u7 = *(const uint2*)(xs + (size_t)c7 * 32 + l * 4);
        float2 p;
        p = bfp2f(u0.x); aL.x += p.x; aL.y += p.y; p = bfp2f(u0.y); aH.x += p.x; aH.y += p.y;
        p = bfp2f(u1.x); aL.x += p.x; aL.y += p.y; p = bfp2f(u1.y); aH.x += p.x; aH.y += p.y;
        p = bfp2f(u2.x); aL.x += p.x; aL.y += p.y; p = bfp2f(u2.y); aH.x += p.x; aH.y += p.y;
        p = bfp2f(u3.x); aL.x += p.x; aL.y += p.y; p = bfp2f(u3.y); aH.x += p.x; aH.y += p.y;
        p = bfp2f(u4.x); aL.x += p.x; aL.y += p.y; p = bfp2f(u4.y); aH.x += p.x; aH.y += p.y;
        p = bfp2f(u5.x); aL.x += p.x; aL.y += p.y; p = bfp2f(u5.y); aH.x += p.x; aH.y += p.y;
        p = bfp2f(u6.x); aL.x += p.x; aL.y += p.y; p = bfp2f(u6.y); aH.x += p.x; aH.y += p.y;
        p = bfp2f(u7.x); aL.x += p.x; aL.y += p.y; p = bfp2f(u7.y); aH.x += p.x; aH.y += p.y;
    }
    for (; i < end; ++i) {
        uint2 u = *(const uint2*)(xs + (size_t)col[i] * 32 + l * 4);
        float2 p;
        p = bfp2f(u.x); aL.x += p.x; aL.y += p.y;
        p = bfp2f(u.y); aH.x += p.x; aH.y += p.y;
    }
    const float dv = dinv[v];
    uint2 o;
    o.x = packbf2(dv * aL.x, dv * aL.y);
    o.y = packbf2(dv * aH.x, dv * aH.y);
    *(uint2*)(xagg + (size_t)v * 32 + l * 4) = o;
}

// ---------------- 64-dim aggregation: 16 lanes/node, uint2 = full 128B row ----------------
__global__ __launch_bounds__(256) void k_agg64(const unsigned short* __restrict__ hsc,
                                               const float* __restrict__ dinv,
                                               const int* __restrict__ rs, const int* __restrict__ col,
                                               unsigned short* __restrict__ out, int n)
{
    const int tid = threadIdx.x;
    const int l   = tid & 15;                 // 4 channels per lane
    const int v   = blockIdx.x * 16 + (tid >> 4);
    if (v >= n) return;

    uint2 sv = *(const uint2*)(hsc + (size_t)v * 64 + l * 4);
    float2 aL = bfp2f(sv.x), aH = bfp2f(sv.y);
    int i = rs[v];
    const int end = rs[v + 1];
    for (; i + 8 <= end; i += 8) {
        int c0 = col[i],     c1 = col[i + 1], c2 = col[i + 2], c3 = col[i + 3];
        int c4 = col[i + 4], c5 = col[i + 5], c6 = col[i + 6], c7 = col[i + 7];
        uint2 u0 = *(const uint2*)(hsc + (size_t)c0 * 64 + l * 4);
        uint2 u1 = *(const uint2*)(hsc + (size_t)c1 * 64 + l * 4);
        uint2 u2 = *(const uint2*)(hsc + (size_t)c2 * 64 + l * 4);
        uint2 u3 = *(const uint2*)(hsc + (size_t)c3 * 64 + l * 4);
        uint2 u4 = *(const uint2*)(hsc + (size_t)c4 * 64 + l * 4);
        uint2 u5 = *(const uint2*)(hsc + (size_t)c5 * 64 + l * 4);
        uint2 u6 = *(const uint2*)(hsc + (size_t)c6 * 64 + l * 4);
        uint2 u7 = *(const uint2*)(hsc + (size_t)c7 * 64 + l * 4);
        float2 p;
        p = bfp2f(u0.x); aL.x += p.x; aL.y += p.y; p = bfp2f(u0.y); aH.x += p.x; aH.y += p.y;
        p = bfp2f(u1.x); aL.x += p.x; aL.y += p.y; p = bfp2f(u1.y); aH.x += p.x; aH.y += p.y;
        p = bfp2f(u2.x); aL.x += p.x; aL.y += p.y; p = bfp2f(u2.y); aH.x += p.x; aH.y += p.y;
        p = bfp2f(u3.x); aL.x += p.x; aL.y += p.y; p = bfp2f(u3.y); aH.x += p.x; aH.y += p.y;
        p = bfp2f(u4.x); aL.x += p.x; aL.y += p.y; p = bfp2f(u4.y); aH.x += p.x; aH.y += p.y;
        p = bfp2f(u5.x); aL.x += p.x; aL.y += p.y; p = bfp2f(u5.y); aH.x += p.x; aH.y += p.y;
        p = bfp2f(u6.x); aL.x += p.x; aL.y += p.y; p = bfp2f(u6.y); aH.x += p.x; aH.y += p.y;
        p = bfp2f(u7.x); aL.x += p.x; aL.y += p.y; p = bfp2f(u7.y); aH.x += p.x; aH.y += p.y;
    }
    for (; i < end; ++i) {
        uint2 u = *(const uint2*)(hsc + (size_t)col[i] * 64 + l * 4);
        float2 p;
        p = bfp2f(u.x); aL.x += p.x; aL.y += p.y;
        p = bfp2f(u.y); aH.x += p.x; aH.y += p.y;
    }
    const float dv = dinv[v];
    uint2 o;
    o.x = packbf2(dv * aL.x, dv * aL.y);
    o.y = packbf2(dv * aH.x, dv * aH.y);
    *(uint2*)(out + (size_t)v * 64 + l * 4) = o;
}

// ---------------- node1: h1s = relu(xagg @ W1 + b1) * dinv ----------------
__global__ __launch_bounds__(256) void k_node1(const unsigned short* __restrict__ xagg,
                                               const short* __restrict__ W1T,
                                               const float* __restrict__ b1, const float* __restrict__ dinv,
                                               unsigned short* __restrict__ h1s, int n)
{
    const int tid = threadIdx.x;
    const int w = tid >> 6, lane = tid & 63, r = lane & 31, kg = lane >> 5;
    const int nb = blockIdx.x * 128 + w * 32;

    bf16x8 a0[2], a1[2];
#pragma unroll
    for (int t = 0; t < 2; ++t) {
        a0[t] = *(const bf16x8*)&W1T[r * 32 + t * 16 + kg * 8];
        a1[t] = *(const bf16x8*)&W1T[(r + 32) * 32 + t * 16 + kg * 8];
    }

    int row = nb + r;
    if (row >= n) row = n - 1;
    f32x16 acc0 = {0.f}, acc1 = {0.f};
#pragma unroll
    for (int t = 0; t < 2; ++t) {
        bf16x8 b = *(const bf16x8*)&xagg[(size_t)row * 32 + t * 16 + kg * 8];
        acc0 = __builtin_amdgcn_mfma_f32_32x32x16_bf16(a0[t], b, acc0, 0, 0, 0);
        acc1 = __builtin_amdgcn_mfma_f32_32x32x16_bf16(a1[t], b, acc1, 0, 0, 0);
    }

    const int node = nb + r;
    if (node < n) {
        const float dv = dinv[node];
#pragma unroll
        for (int q = 0; q < 4; ++q) {
            const int j0 = 8 * q + 4 * kg;
            float4 bA = *(const float4*)&b1[j0];
            float4 bB = *(const float4*)&b1[j0 + 32];
            short4 s0, s1;
            float t0, t1;
            t0 = acc0[4 * q]     + bA.x; t0 = t0 > 0.f ? t0 : 0.f; s0.x = f2bf(t0 * dv);
            t0 = acc0[4 * q + 1] + bA.y; t0 = t0 > 0.f ? t0 : 0.f; s0.y = f2bf(t0 * dv);
            t0 = acc0[4 * q + 2] + bA.z; t0 = t0 > 0.f ? t0 : 0.f; s0.z = f2bf(t0 * dv);
            t0 = acc0[4 * q + 3] + bA.w; t0 = t0 > 0.f ? t0 : 0.f; s0.w = f2bf(t0 * dv);
            t1 = acc1[4 * q]     + bB.x; t1 = t1 > 0.f ? t1 : 0.f; s1.x = f2bf(t1 * dv);
            t1 = acc1[4 * q + 1] + bB.y; t1 = t1 > 0.f ? t1 : 0.f; s1.y = f2bf(t1 * dv);
            t1 = acc1[4 * q + 2] + bB.z; t1 = t1 > 0.f ? t1 : 0.f; s1.z = f2bf(t1 * dv);
            t1 = acc1[4 * q + 3] + bB.w; t1 = t1 > 0.f ? t1 : 0.f; s1.w = f2bf(t1 * dv);
            *(short4*)&h1s[(size_t)node * 64 + j0]      = s0;
            *(short4*)&h1s[(size_t)node * 64 + j0 + 32] = s1;
        }
    }
}

// ---------------- node2: h2 = xagg2 @ W2 + b2 ----------------
__global__ __launch_bounds__(256) void k_node2(const unsigned short* __restrict__ xagg2,
                                               const short* __restrict__ W2T,
                                               const float* __restrict__ b2,
                                               unsigned short* __restrict__ h2, int n)
{
    const int tid = threadIdx.x;
    const int w = tid >> 6, lane = tid & 63, r = lane & 31, kg = lane >> 5;
    const int nb = blockIdx.x * 128 + w * 32;

    bf16x8 a0[4], a1[4];
#pragma unroll
    for (int t = 0; t < 4; ++t) {
        a0[t] = *(const bf16x8*)&W2T[r * 64 + t * 16 + kg * 8];
        a1[t] = *(const bf16x8*)&W2T[(r + 32) * 64 + t * 16 + kg * 8];
    }

    int row = nb + r;
    if (row >= n) row = n - 1;
    f32x16 acc0 = {0.f}, acc1 = {0.f};
#pragma unroll
    for (int t = 0; t < 4; ++t) {
        bf16x8 b = *(const bf16x8*)&xagg2[(size_t)row * 64 + t * 16 + kg * 8];
        acc0 = __builtin_amdgcn_mfma_f32_32x32x16_bf16(a0[t], b, acc0, 0, 0, 0);
        acc1 = __builtin_amdgcn_mfma_f32_32x32x16_bf16(a1[t], b, acc1, 0, 0, 0);
    }

    const int node = nb + r;
    if (node < n) {
#pragma unroll
        for (int q = 0; q < 4; ++q) {
            const int j0 = 8 * q + 4 * kg;
            float4 bA = *(const float4*)&b2[j0];
            float4 bB = *(const float4*)&b2[j0 + 32];
            short4 s0, s1;
            s0.x = f2bf(acc0[4 * q]     + bA.x); s0.y = f2bf(acc0[4 * q + 1] + bA.y);
            s0.z = f2bf(acc0[4 * q + 2] + bA.z); s0.w = f2bf(acc0[4 * q + 3] + bA.w);
            s1.x = f2bf(acc1[4 * q]     + bB.x); s1.y = f2bf(acc1[4 * q + 1] + bB.y);
            s1.z = f2bf(acc1[4 * q + 2] + bB.z); s1.w = f2bf(acc1[4 * q + 3] + bB.w);
            *(short4*)&h2[(size_t)node * 64 + j0]      = s0;
            *(short4*)&h2[(size_t)node * 64 + j0 + 32] = s1;
        }
    }
}

// ---------------- MFMA edge MLP ----------------
// hid packed: u32[c] = (col c, col c+32) at byte (4c)^((row&7)<<4) in 128B row.
__global__ __launch_bounds__(256) void k_edge_mlp_mfma(
    const unsigned short* __restrict__ h2bf, const float* __restrict__ eattr,
    const int* __restrict__ ei,
    const short* __restrict__ Wc1T, const float* __restrict__ bc1,
    const short* __restrict__ Wc2T, const float* __restrict__ bc2,
    float* __restrict__ out, int E)
{
    __shared__ char slab[4 * 8192];   // 32 KB

    const int tid = threadIdx.x;
    const int w = tid >> 6, lane = tid & 63, r = lane & 31, kg = lane >> 5;
    const int q = lane & 3, sr = lane >> 2;

    char* myslab = slab + w * 8192;

    const long eb = (long)blockIdx.x * 128 + w * 32;
    long ecl = eb + r; if (ecl >= E) ecl = E - 1;
    const int ns = ei[ecl];
    const int nd = ei[E + ecl];

    // attr fragment (f32 direct)
    bf16x8 aa;
    {
        const float* arow = &eattr[(size_t)ecl * 16];
        float4 alo = *(const float4*)&arow[kg * 8];
        float4 ahi = *(const float4*)&arow[kg * 8 + 4];
        aa[0] = f2bf(alo.x); aa[1] = f2bf(alo.y); aa[2] = f2bf(alo.z); aa[3] = f2bf(alo.w);
        aa[4] = f2bf(ahi.x); aa[5] = f2bf(ahi.y); aa[6] = f2bf(ahi.z); aa[7] = f2bf(ahi.w);
    }

    // coop gathers: 4-lane groups fetch contiguous 64B per row
    {
        int n0 = __shfl(ns, sr);
        int n1 = __shfl(ns, 16 + sr);
        int m0 = __shfl(nd, sr);
        int m1 = __shfl(nd, 16 + sr);
        int4 s0 = *(const int4*)&h2bf[(size_t)n0 * 64 + q * 8];
        int4 s1 = *(const int4*)&h2bf[(size_t)n0 * 64 + 32 + q * 8];
        int4 s2 = *(const int4*)&h2bf[(size_t)n1 * 64 + q * 8];
        int4 s3 = *(const int4*)&h2bf[(size_t)n1 * 64 + 32 + q * 8];
        int4 d0 = *(const int4*)&h2bf[(size_t)m0 * 64 + q * 8];
        int4 d1 = *(const int4*)&h2bf[(size_t)m0 * 64 + 32 + q * 8];
        int4 d2 = *(const int4*)&h2bf[(size_t)m1 * 64 + q * 8];
        int4 d3 = *(const int4*)&h2bf[(size_t)m1 * 64 + 32 + q * 8];
        const int x0 = (sr ^ q) * 16, x1 = (16 + (sr ^ q)) * 16;
        *(int4*)(myslab + q * 512 + x0)              = s0;
        *(int4*)(myslab + (4 + q) * 512 + x0)        = s1;
        *(int4*)(myslab + q * 512 + x1)              = s2;
        *(int4*)(myslab + (4 + q) * 512 + x1)        = s3;
        *(int4*)(myslab + 4096 + q * 512 + x0)       = d0;
        *(int4*)(myslab + 4096 + (4 + q) * 512 + x0) = d1;
        *(int4*)(myslab + 4096 + q * 512 + x1)       = d2;
        *(int4*)(myslab + 4096 + (4 + q) * 512 + x1) = d3;
    }

    f32x16 acc0, acc1;
    const float bias0 = bc1[r], bias1 = bc1[r + 32];
#pragma unroll
    for (int i = 0; i < 16; ++i) { acc0[i] = bias0; acc1[i] = bias1; }

#pragma unroll
    for (int t = 0; t < 4; ++t) {
        const int c = 2 * t + kg;
        bf16x8 a  = *(const bf16x8*)(myslab + c * 512 + ((r ^ (c & 3)) * 16));
        bf16x8 w0 = *(const bf16x8*)&Wc1T[r * 144 + t * 16 + kg * 8];
        bf16x8 w1 = *(const bf16x8*)&Wc1T[(r + 32) * 144 + t * 16 + kg * 8];
        acc0 = __builtin_amdgcn_mfma_f32_32x32x16_bf16(a, w0, acc0, 0, 0, 0);
        acc1 = __builtin_amdgcn_mfma_f32_32x32x16_bf16(a, w1, acc1, 0, 0, 0);
    }
#pragma unroll
    for (int t = 0; t < 4; ++t) {
        const int c = 2 * t + kg;
        bf16x8 a  = *(const bf16x8*)(myslab + 4096 + c * 512 + ((r ^ (c & 3)) * 16));
        bf16x8 w0 = *(const bf16x8*)&Wc1T[r * 144 + (4 + t) * 16 + kg * 8];
        bf16x8 w1 = *(const bf16x8*)&Wc1T[(r + 32) * 144 + (4 + t) * 16 + kg * 8];
        acc0 = __builtin_amdgcn_mfma_f32_32x32x16_bf16(a, w0, acc0, 0, 0, 0);
        acc1 = __builtin_amdgcn_mfma_f32_32x32x16_bf16(a, w1, acc1, 0, 0, 0);
    }
    {
        bf16x8 w0 = *(const bf16x8*)&Wc1T[r * 144 + 128 + kg * 8];
        bf16x8 w1 = *(const bf16x8*)&Wc1T[(r + 32) * 144 + 128 + kg * 8];
        acc0 = __builtin_amdgcn_mfma_f32_32x32x16_bf16(aa, w0, acc0, 0, 0, 0);
        acc1 = __builtin_amdgcn_mfma_f32_32x32x16_bf16(aa, w1, acc1, 0, 0, 0);
    }

    // epilogue 1: relu -> packed u32 (col r, col r+32) -> swizzled hid (src half)
#pragma unroll
    for (int reg = 0; reg < 16; ++reg) {
        const int row = (reg & 3) + 8 * (reg >> 2) + 4 * kg;
        float v0 = acc0[reg]; v0 = v0 > 0.f ? v0 : 0.f;
        float v1 = acc1[reg]; v1 = v1 > 0.f ? v1 : 0.f;
        *(unsigned*)(myslab + row * 128 + ((4 * r) ^ ((row & 7) << 4))) = packbf2(v0, v1);
    }

    // layer 2: A-frag = 16B chunk m = t2*2+kg of own row r (k-space permuted to match Wc2T)
    const float bias2 = (r < 5) ? bc2[r] : 0.f;
    f32x16 acc2;
#pragma unroll
    for (int i = 0; i < 16; ++i) acc2[i] = bias2;
#pragma unroll
    for (int t2 = 0; t2 < 4; ++t2) {
        const int m = t2 * 2 + kg;
        bf16x8 a  = *(const bf16x8*)(myslab + r * 128 + ((16 * m) ^ ((r & 7) << 4)));
        bf16x8 bw = *(const bf16x8*)&Wc2T[r * 64 + t2 * 16 + kg * 8];
        acc2 = __builtin_amdgcn_mfma_f32_32x32x16_bf16(a, bw, acc2, 0, 0, 0);
    }

    // stores (edge order: contiguous 640B per wave)
#pragma unroll
    for (int reg = 0; reg < 16; ++reg) {
        const int row = (reg & 3) + 8 * (reg >> 2) + 4 * kg;
        const long eo = eb + row;
        if (r < 5 && eo < E) out[(size_t)eo * 5 + r] = acc2[reg];
    }
}

extern "C" void kernel_launch(void* const* d_in, const int* in_sizes, int n_in,
                              void* d_out, int out_size, void* d_ws, size_t ws_size,
                              hipStream_t stream)
{
    const float* x     = (const float*)d_in[0];
    const int*   ei    = (const int*)d_in[1];
    const float* eattr = (const float*)d_in[2];
    const float* W1    = (const float*)d_in[3];
    const float* b1    = (const float*)d_in[4];
    const float* W2    = (const float*)d_in[5];
    const float* b2    = (const float*)d_in[6];
    const float* Wc1   = (const float*)d_in[7];
    const float* bc1   = (const float*)d_in[8];
    const float* Wc2   = (const float*)d_in[9];
    const float* bc2   = (const float*)d_in[10];
    float* outp = (float*)d_out;

    const int N = in_sizes[0] / 32;
    const int E = in_sizes[1] / 2;
    const int nbk = (N + 255) >> 8;

    // ---- carve workspace ----
    size_t off = 0;
    char* base = (char*)d_ws;
    auto carve = [&](size_t bytes) -> void* {
        void* p = base + off;
        off += (bytes + 255) & ~(size_t)255;
        return p;
    };
    int*   bcnt   = (int*)carve(1024 * 4);           // bcnt + bcur adjacent
    int*   bcur   = bcnt + 512;
    int*   bstart = (int*)carve(520 * 4);
    float* dinv   = (float*)carve((size_t)N * 4);
    int*   rs     = (int*)carve((size_t)(N + 1) * 4);
    int*   col    = (int*)carve((size_t)E * 4);
    int2*  ebs    = (int2*)carve((size_t)E * 8);
    unsigned short* xs    = (unsigned short*)carve((size_t)N * 32 * 2);
    unsigned short* xagg  = (unsigned short*)carve((size_t)N * 32 * 2);
    unsigned short* h1s   = (unsigned short*)carve((size_t)N * 64 * 2);
    unsigned short* xagg2 = (unsigned short*)carve((size_t)N * 64 * 2);
    unsigned short* h2bf  = h1s;   // alias: h1s dead after k_agg64 reads it
    short* Wc1T   = (short*)carve(9216 * 2);
    short* Wc2T   = (short*)carve(2048 * 2);
    short* W2T    = (short*)carve(4096 * 2);
    short* W1T    = (short*)carve(2048 * 2);
    (void)n_in; (void)out_size; (void)ws_size;

    const int NAX = (N + 31) / 32;       // agg_x: 32 nodes/block
    const int NA  = (N + 15) / 16;       // agg64: 16 nodes/block
    const int NM  = (N + 127) / 128;     // node MM: 128 nodes/block
    const int NT  = (E + 127) / 128;     // edge-MLP: 128 edges/block
    const int NSC = (E + 4095) / 4096;   // binscatter chunks

    hipMemsetAsync(bcnt, 0, 1024 * 4, stream);

    k_prep<<<68, 256, 0, stream>>>(Wc1, Wc2, W2, W1, Wc1T, Wc2T, W2T, W1T);

    // ---- bucketed CSR build (+ fused xs) ----
    k_bcount<<<1024, 256, 0, stream>>>(ei, bcnt, E);
    k_bscan<<<1, 512, 0, stream>>>(bcnt, nbk, bstart);
    k_binscatter<<<NSC, 256, 0, stream>>>(ei, bstart, bcur, ebs, E);
    k_build<<<nbk, 256, 0, stream>>>(ebs, bstart, rs, col, dinv, x, xs, N, E);

    // ---- GCN layers ----
    k_agg_x<<<NAX, 256, 0, stream>>>(xs, dinv, rs, col, xagg, N);
    k_node1<<<NM, 256, 0, stream>>>(xagg, W1T, b1, dinv, h1s, N);
    k_agg64<<<NA, 256, 0, stream>>>(h1s, dinv, rs, col, xagg2, N);
    k_node2<<<NM, 256, 0, stream>>>(xagg2, W2T, b2, h2bf, N);

    // ---- edge MLP ----
    k_edge_mlp_mfma<<<NT, 256, 0, stream>>>(h2bf, eattr, ei, Wc1T, bc1, Wc2T, bc2, outp, E);
}